// Round 1
// baseline (440.026 us; speedup 1.0000x reference)
//
#include <hip/hip_runtime.h>
#include <cstdint>
#include <cstddef>

// ---------- types & helpers ----------
typedef __attribute__((ext_vector_type(4))) float f32x4;
typedef __attribute__((ext_vector_type(8))) short bf16x8;
typedef __attribute__((ext_vector_type(4))) unsigned short u16x4;

#define GPTR(p) ((const __attribute__((address_space(1))) void*)(p))
#define LPTR(p) ((__attribute__((address_space(3))) void*)(p))

static constexpr int BB = 4096;  // batch rows
static constexpr int DD = 1024;  // feature dim
static constexpr int FF = 8192;  // memory slots
static constexpr int MM = 256;   // attention key dim

__device__ __forceinline__ unsigned short f2bf(float f) {
    union { float f; unsigned u; } x; x.f = f;
    return (unsigned short)((x.u + 0x7FFFu + ((x.u >> 16) & 1u)) >> 16);  // RNE
}

// ---------- f32 -> bf16 convert (vectorized) ----------
__global__ __launch_bounds__(256) void cvt_bf16(const float* __restrict__ in,
                                                unsigned short* __restrict__ out, int n) {
    int i = (blockIdx.x * 256 + threadIdx.x) * 4;
    if (i >= n) return;
    f32x4 v = *(const f32x4*)(in + i);
    u16x4 o;
    o.x = f2bf(v.x); o.y = f2bf(v.y); o.z = f2bf(v.z); o.w = f2bf(v.w);
    *(u16x4*)(out + i) = o;
}

// ---------- generic C = (A @ B^T + bias) * scale,  A[Mo][Kd], B[No][Kd] bf16 ----------
// 128x128 tile, BK=32, 4 waves (2x2), each wave 64x64 via 4x4 frags of 16x16x32 MFMA.
// global_load_lds width-16 staging (m97 structure).
template<int OUT_BF16, int BIAS_MODE>  // BIAS_MODE: 0 none, 1 by-col, 2 by-row
__global__ __launch_bounds__(256) void gemm_bt(
    const unsigned short* __restrict__ A,
    const unsigned short* __restrict__ Bm,
    void* __restrict__ Cout,
    const float* __restrict__ bias,
    int Mo, int No, int Kd, float scale)
{
    __shared__ alignas(16) unsigned short As[128 * 32];
    __shared__ alignas(16) unsigned short Bs[128 * 32];

    const int tid  = threadIdx.x;
    const int lane = tid & 63;
    const int wid  = tid >> 6;
    const int ntile = No >> 7;
    const int tm = (blockIdx.x / ntile) << 7;
    const int tn = (blockIdx.x % ntile) << 7;
    const int wm = (wid >> 1) * 64;
    const int wn = (wid & 1) * 64;
    const int lr = lane & 15;
    const int lg = lane >> 4;

    f32x4 acc[4][4] = {};

    // staging: thread t covers row t/4, cols (t%4)*8 .. +7 (8 bf16 = 16B)
    const int srow = tid >> 2;
    const int scol = (tid & 3) << 3;
    const unsigned short* aptr = A  + (size_t)(tm + srow) * Kd + scol;
    const unsigned short* bptr = Bm + (size_t)(tn + srow) * Kd + scol;
    unsigned short* As_base = &As[wid * 512];   // HW adds lane*16B
    unsigned short* Bs_base = &Bs[wid * 512];

    for (int k0 = 0; k0 < Kd; k0 += 32) {
        __builtin_amdgcn_global_load_lds(GPTR(aptr + k0),                      LPTR(As_base),        16, 0, 0);
        __builtin_amdgcn_global_load_lds(GPTR(aptr + (size_t)64 * Kd + k0),    LPTR(As_base + 2048), 16, 0, 0);
        __builtin_amdgcn_global_load_lds(GPTR(bptr + k0),                      LPTR(Bs_base),        16, 0, 0);
        __builtin_amdgcn_global_load_lds(GPTR(bptr + (size_t)64 * Kd + k0),    LPTR(Bs_base + 2048), 16, 0, 0);
        __syncthreads();

        bf16x8 af[4], bfr[4];
        #pragma unroll
        for (int mi = 0; mi < 4; ++mi)
            af[mi] = *(const bf16x8*)&As[(wm + mi * 16 + lr) * 32 + lg * 8];
        #pragma unroll
        for (int ni = 0; ni < 4; ++ni)
            bfr[ni] = *(const bf16x8*)&Bs[(wn + ni * 16 + lr) * 32 + lg * 8];

        #pragma unroll
        for (int mi = 0; mi < 4; ++mi)
            #pragma unroll
            for (int ni = 0; ni < 4; ++ni)
                acc[mi][ni] = __builtin_amdgcn_mfma_f32_16x16x32_bf16(af[mi], bfr[ni], acc[mi][ni], 0, 0, 0);
        __syncthreads();
    }

    // epilogue: C[row][col], row = tm+wm+mi*16+lg*4+r, col = tn+wn+ni*16+lr
    #pragma unroll
    for (int mi = 0; mi < 4; ++mi) {
        #pragma unroll
        for (int ni = 0; ni < 4; ++ni) {
            #pragma unroll
            for (int r = 0; r < 4; ++r) {
                const int row = tm + wm + mi * 16 + lg * 4 + r;
                const int col = tn + wn + ni * 16 + lr;
                float v = acc[mi][ni][r];
                if (BIAS_MODE == 1) v += bias[col];
                if (BIAS_MODE == 2) v += bias[row];
                v *= scale;
                if (OUT_BF16) ((unsigned short*)Cout)[(size_t)row * No + col] = f2bf(v);
                else          ((float*)Cout)[(size_t)row * No + col] = v;
            }
        }
    }
}

// ---------- sparsemax over rows of S [BB][FF], in place; bf16 copy to Ab ----------
// One block per row; 8192 values held in registers (32/thread). Bisection on tau
// (f(tau)=sum(max(z-tau,0)) is monotone, root in [max-1, max]) + one exact refine.
__global__ __launch_bounds__(256) void sparsemax_k(float* __restrict__ S,
                                                   unsigned short* __restrict__ Ab)
{
    __shared__ float red[8];
    const int t = threadIdx.x;
    const int w = t >> 6, lane = t & 63;
    float* Z = S + (size_t)blockIdx.x * FF;
    unsigned short* Arow = Ab + (size_t)blockIdx.x * FF;

    f32x4 z[8];
    #pragma unroll
    for (int j = 0; j < 8; ++j)
        z[j] = *(const f32x4*)&Z[j * 1024 + t * 4];

    // row max
    float mx = -1e30f;
    #pragma unroll
    for (int j = 0; j < 8; ++j)
        mx = fmaxf(mx, fmaxf(fmaxf(z[j].x, z[j].y), fmaxf(z[j].z, z[j].w)));
    #pragma unroll
    for (int off = 32; off > 0; off >>= 1) mx = fmaxf(mx, __shfl_xor(mx, off));
    if (lane == 0) red[w] = mx;
    __syncthreads();
    mx = fmaxf(fmaxf(red[0], red[1]), fmaxf(red[2], red[3]));
    __syncthreads();

    float lo = mx - 1.0f, hi = mx;
    for (int it = 0; it < 24; ++it) {
        const float mid = 0.5f * (lo + hi);
        float s = 0.0f;
        #pragma unroll
        for (int j = 0; j < 8; ++j) {
            s += fmaxf(z[j].x - mid, 0.0f);
            s += fmaxf(z[j].y - mid, 0.0f);
            s += fmaxf(z[j].z - mid, 0.0f);
            s += fmaxf(z[j].w - mid, 0.0f);
        }
        #pragma unroll
        for (int off = 32; off > 0; off >>= 1) s += __shfl_xor(s, off);
        if (lane == 0) red[w] = s;
        __syncthreads();
        s = red[0] + red[1] + red[2] + red[3];
        __syncthreads();
        if (s >= 1.0f) lo = mid; else hi = mid;
    }

    // exact refine: {z > lo} is a superset of the support; tau = (sum-1)/k
    float s = 0.0f, cnt = 0.0f;
    #pragma unroll
    for (int j = 0; j < 8; ++j) {
        #pragma unroll
        for (int c = 0; c < 4; ++c) {
            const float v = z[j][c];
            if (v > lo) { s += v; cnt += 1.0f; }
        }
    }
    #pragma unroll
    for (int off = 32; off > 0; off >>= 1) { s += __shfl_xor(s, off); cnt += __shfl_xor(cnt, off); }
    if (lane == 0) { red[w] = s; red[4 + w] = cnt; }
    __syncthreads();
    s   = red[0] + red[1] + red[2] + red[3];
    cnt = red[4] + red[5] + red[6] + red[7];
    const float tau = (s - 1.0f) / cnt;

    #pragma unroll
    for (int j = 0; j < 8; ++j) {
        f32x4 a;
        a.x = fmaxf(z[j].x - tau, 0.0f);
        a.y = fmaxf(z[j].y - tau, 0.0f);
        a.z = fmaxf(z[j].z - tau, 0.0f);
        a.w = fmaxf(z[j].w - tau, 0.0f);
        *(f32x4*)&Z[j * 1024 + t * 4] = a;
        u16x4 o;
        o.x = f2bf(a.x); o.y = f2bf(a.y); o.z = f2bf(a.z); o.w = f2bf(a.w);
        *(u16x4*)&Arow[j * 1024 + t * 4] = o;
    }
}

// ---------- launch ----------
extern "C" void kernel_launch(void* const* d_in, const int* in_sizes, int n_in,
                              void* d_out, int out_size, void* d_ws, size_t ws_size,
                              hipStream_t stream) {
    const float* x  = (const float*)d_in[0];
    const float* Xd = (const float*)d_in[1];
    const float* Wq = (const float*)d_in[2];
    const float* bq = (const float*)d_in[3];
    const float* Wk = (const float*)d_in[4];
    const float* bk = (const float*)d_in[5];
    const float* Wv = (const float*)d_in[6];
    const float* bv = (const float*)d_in[7];

    float* out       = (float*)d_out;
    float* out_xhat  = out + (size_t)BB * DD;
    float* out_attn  = out + (size_t)2 * BB * DD;   // scores staged here, sparsemax in place

    char* w = (char*)d_ws;
    unsigned short* xb  = (unsigned short*)w; w += (size_t)BB * DD * 2;
    unsigned short* Xb  = (unsigned short*)w; w += (size_t)FF * DD * 2;
    unsigned short* Wqb = (unsigned short*)w; w += (size_t)MM * DD * 2;
    unsigned short* Wkb = (unsigned short*)w; w += (size_t)MM * DD * 2;
    unsigned short* Wvb = (unsigned short*)w; w += (size_t)DD * DD * 2;
    unsigned short* Qb  = (unsigned short*)w; w += (size_t)BB * MM * 2;
    unsigned short* Kb  = (unsigned short*)w; w += (size_t)FF * MM * 2;
    unsigned short* Vtb = (unsigned short*)w; w += (size_t)DD * FF * 2;  // Vt[D][F]
    unsigned short* Ab  = (unsigned short*)w; w += (size_t)BB * FF * 2;  // attn bf16

    // output 0: x passthrough
    hipMemcpyAsync(d_out, d_in[0], (size_t)BB * DD * sizeof(float),
                   hipMemcpyDeviceToDevice, stream);

    // bf16 conversions of all GEMM inputs
    cvt_bf16<<<BB * DD / 1024, 256, 0, stream>>>(x,  xb,  BB * DD);
    cvt_bf16<<<FF * DD / 1024, 256, 0, stream>>>(Xd, Xb,  FF * DD);
    cvt_bf16<<<MM * DD / 1024, 256, 0, stream>>>(Wq, Wqb, MM * DD);
    cvt_bf16<<<MM * DD / 1024, 256, 0, stream>>>(Wk, Wkb, MM * DD);
    cvt_bf16<<<DD * DD / 1024, 256, 0, stream>>>(Wv, Wvb, DD * DD);

    const float scl = 0.0625f;  // 1/sqrt(256)

    // Q = (x @ Wq^T + bq) * scl           [BB,MM] bf16
    gemm_bt<1, 1><<<(BB / 128) * (MM / 128), 256, 0, stream>>>(xb, Wqb, Qb, bq, BB, MM, DD, scl);
    // K = (X @ Wk^T + bk) * scl           [FF,MM] bf16
    gemm_bt<1, 1><<<(FF / 128) * (MM / 128), 256, 0, stream>>>(Xb, Wkb, Kb, bk, FF, MM, DD, scl);
    // Vt = Wv @ X^T + bv[row]             [DD,FF] bf16  (= V^T)
    gemm_bt<1, 2><<<(DD / 128) * (FF / 128), 256, 0, stream>>>(Wvb, Xb, Vtb, bv, DD, FF, DD, 1.0f);
    // scores = Q @ K^T                    [BB,FF] f32 -> d_out attn slot
    gemm_bt<0, 0><<<(BB / 128) * (FF / 128), 256, 0, stream>>>(Qb, Kb, out_attn, nullptr, BB, FF, MM, 1.0f);
    // sparsemax rows, in place + bf16 copy
    sparsemax_k<<<BB, 256, 0, stream>>>(out_attn, Ab);
    // x_hat = attn @ Vt^T                 [BB,DD] f32
    gemm_bt<0, 0><<<(BB / 128) * (DD / 128), 256, 0, stream>>>(Ab, Vtb, out_xhat, nullptr, BB, DD, FF, 1.0f);
}

// Round 2
// 337.345 us; speedup vs baseline: 1.3044x; 1.3044x over previous
//
#include <hip/hip_runtime.h>
#include <cstdint>
#include <cstddef>

// ---------- types & helpers ----------
typedef __attribute__((ext_vector_type(4))) float f32x4;
typedef __attribute__((ext_vector_type(8))) short bf16x8;
typedef __attribute__((ext_vector_type(4))) unsigned short u16x4;
typedef __attribute__((ext_vector_type(8))) unsigned short u16x8;

#define GPTR(p) ((const __attribute__((address_space(1))) void*)(p))
#define LPTR(p) ((__attribute__((address_space(3))) void*)(p))

static constexpr int BB = 4096;  // batch rows
static constexpr int DD = 1024;  // feature dim
static constexpr int FF = 8192;  // memory slots
static constexpr int MM = 256;   // attention key dim

__device__ __forceinline__ unsigned short f2bf(float f) {
    union { float f; unsigned u; } x; x.f = f;
    return (unsigned short)((x.u + 0x7FFFu + ((x.u >> 16) & 1u)) >> 16);  // RNE
}
__device__ __forceinline__ float bf2f(unsigned short h) {
    union { unsigned u; float f; } x; x.u = ((unsigned)h) << 16;
    return x.f;
}
// bijective XCD swizzle (grid % 8 == 0): consecutive logical ids land on one XCD
__device__ __forceinline__ int xcd_swz(int bid, int grid) {
    const int cpx = grid >> 3;
    return (bid & 7) * cpx + (bid >> 3);
}

// ---------- f32 -> bf16 convert (vectorized) ----------
__global__ __launch_bounds__(256) void cvt_bf16(const float* __restrict__ in,
                                                unsigned short* __restrict__ out, int n) {
    int i = (blockIdx.x * 256 + threadIdx.x) * 4;
    if (i >= n) return;
    f32x4 v = *(const f32x4*)(in + i);
    u16x4 o;
    o.x = f2bf(v.x); o.y = f2bf(v.y); o.z = f2bf(v.z); o.w = f2bf(v.w);
    *(u16x4*)(out + i) = o;
}

// ---------- generic C = (A @ B^T + bias) * scale,  A[Mo][Kd], B[No][Kd] bf16 ----------
// 128x128 tile, BK=32, 4 waves (2x2), each wave 64x64 via 4x4 frags of 16x16x32 MFMA.
template<int OUT_BF16, int BIAS_MODE>  // BIAS_MODE: 0 none, 1 by-col, 2 by-row
__global__ __launch_bounds__(256) void gemm_bt(
    const unsigned short* __restrict__ A,
    const unsigned short* __restrict__ Bm,
    void* __restrict__ Cout,
    const float* __restrict__ bias,
    int Mo, int No, int Kd, float scale)
{
    __shared__ alignas(16) unsigned short As[128 * 32];
    __shared__ alignas(16) unsigned short Bs[128 * 32];

    const int tid  = threadIdx.x;
    const int lane = tid & 63;
    const int wid  = tid >> 6;
    const int ntile = No >> 7;
    const int L = xcd_swz(blockIdx.x, gridDim.x);
    const int tm = (L / ntile) << 7;
    const int tn = (L % ntile) << 7;
    const int wm = (wid >> 1) * 64;
    const int wn = (wid & 1) * 64;
    const int lr = lane & 15;
    const int lg = lane >> 4;

    f32x4 acc[4][4] = {};

    const int srow = tid >> 2;
    const int scol = (tid & 3) << 3;
    const unsigned short* aptr = A  + (size_t)(tm + srow) * Kd + scol;
    const unsigned short* bptr = Bm + (size_t)(tn + srow) * Kd + scol;
    unsigned short* As_base = &As[wid * 512];   // HW adds lane*16B
    unsigned short* Bs_base = &Bs[wid * 512];

    for (int k0 = 0; k0 < Kd; k0 += 32) {
        __builtin_amdgcn_global_load_lds(GPTR(aptr + k0),                   LPTR(As_base),        16, 0, 0);
        __builtin_amdgcn_global_load_lds(GPTR(aptr + (size_t)64 * Kd + k0), LPTR(As_base + 2048), 16, 0, 0);
        __builtin_amdgcn_global_load_lds(GPTR(bptr + k0),                   LPTR(Bs_base),        16, 0, 0);
        __builtin_amdgcn_global_load_lds(GPTR(bptr + (size_t)64 * Kd + k0), LPTR(Bs_base + 2048), 16, 0, 0);
        __syncthreads();

        bf16x8 af[4], bfr[4];
        #pragma unroll
        for (int mi = 0; mi < 4; ++mi)
            af[mi] = *(const bf16x8*)&As[(wm + mi * 16 + lr) * 32 + lg * 8];
        #pragma unroll
        for (int ni = 0; ni < 4; ++ni)
            bfr[ni] = *(const bf16x8*)&Bs[(wn + ni * 16 + lr) * 32 + lg * 8];

        #pragma unroll
        for (int mi = 0; mi < 4; ++mi)
            #pragma unroll
            for (int ni = 0; ni < 4; ++ni)
                acc[mi][ni] = __builtin_amdgcn_mfma_f32_16x16x32_bf16(af[mi], bfr[ni], acc[mi][ni], 0, 0, 0);
        __syncthreads();
    }

    #pragma unroll
    for (int mi = 0; mi < 4; ++mi) {
        #pragma unroll
        for (int ni = 0; ni < 4; ++ni) {
            #pragma unroll
            for (int r = 0; r < 4; ++r) {
                const int row = tm + wm + mi * 16 + lg * 4 + r;
                const int col = tn + wn + ni * 16 + lr;
                float v = acc[mi][ni][r];
                if (BIAS_MODE == 1) v += bias[col];
                if (BIAS_MODE == 2) v += bias[row];
                v *= scale;
                if (OUT_BF16) ((unsigned short*)Cout)[(size_t)row * No + col] = f2bf(v);
                else          ((float*)Cout)[(size_t)row * No + col] = v;
            }
        }
    }
}

// ---------- split-K x_hat GEMM: P[kc] = Ab[.,kc-chunk] @ Vtb[.,kc-chunk]^T  (bf16 partials) ----------
// A [BB][FF], B [DD][FF], 4 K-chunks of 2048; grid 1024 = 4 kc x 32 m x 8 n, XCD-swizzled.
__global__ __launch_bounds__(256) void gemm_xhat_sk(
    const unsigned short* __restrict__ A,
    const unsigned short* __restrict__ Bm,
    unsigned short* __restrict__ P)     // [4][BB][DD] bf16 partials
{
    __shared__ alignas(16) unsigned short As[128 * 32];
    __shared__ alignas(16) unsigned short Bs[128 * 32];

    const int tid  = threadIdx.x;
    const int lane = tid & 63;
    const int wid  = tid >> 6;
    const int L  = xcd_swz(blockIdx.x, 1024);
    const int tm = (L & 31) << 7;          // 32 m-tiles (fastest: same B-tile stays in L2)
    const int tn = ((L >> 5) & 7) << 7;    // 8 n-tiles
    const int kc = L >> 8;                 // 4 k-chunks
    const int kbase = kc * 2048;
    const int wm = (wid >> 1) * 64;
    const int wn = (wid & 1) * 64;
    const int lr = lane & 15;
    const int lg = lane >> 4;

    f32x4 acc[4][4] = {};

    const int srow = tid >> 2;
    const int scol = (tid & 3) << 3;
    const unsigned short* aptr = A  + (size_t)(tm + srow) * FF + kbase + scol;
    const unsigned short* bptr = Bm + (size_t)(tn + srow) * FF + kbase + scol;
    unsigned short* As_base = &As[wid * 512];
    unsigned short* Bs_base = &Bs[wid * 512];

    for (int k0 = 0; k0 < 2048; k0 += 32) {
        __builtin_amdgcn_global_load_lds(GPTR(aptr + k0),                   LPTR(As_base),        16, 0, 0);
        __builtin_amdgcn_global_load_lds(GPTR(aptr + (size_t)64 * FF + k0), LPTR(As_base + 2048), 16, 0, 0);
        __builtin_amdgcn_global_load_lds(GPTR(bptr + k0),                   LPTR(Bs_base),        16, 0, 0);
        __builtin_amdgcn_global_load_lds(GPTR(bptr + (size_t)64 * FF + k0), LPTR(Bs_base + 2048), 16, 0, 0);
        __syncthreads();

        bf16x8 af[4], bfr[4];
        #pragma unroll
        for (int mi = 0; mi < 4; ++mi)
            af[mi] = *(const bf16x8*)&As[(wm + mi * 16 + lr) * 32 + lg * 8];
        #pragma unroll
        for (int ni = 0; ni < 4; ++ni)
            bfr[ni] = *(const bf16x8*)&Bs[(wn + ni * 16 + lr) * 32 + lg * 8];

        #pragma unroll
        for (int mi = 0; mi < 4; ++mi)
            #pragma unroll
            for (int ni = 0; ni < 4; ++ni)
                acc[mi][ni] = __builtin_amdgcn_mfma_f32_16x16x32_bf16(af[mi], bfr[ni], acc[mi][ni], 0, 0, 0);
        __syncthreads();
    }

    unsigned short* Pk = P + (size_t)kc * BB * DD;
    #pragma unroll
    for (int mi = 0; mi < 4; ++mi)
        #pragma unroll
        for (int ni = 0; ni < 4; ++ni)
            #pragma unroll
            for (int r = 0; r < 4; ++r) {
                const int row = tm + wm + mi * 16 + lg * 4 + r;
                const int col = tn + wn + ni * 16 + lr;
                Pk[(size_t)row * DD + col] = f2bf(acc[mi][ni][r]);
            }
}

// ---------- reduce 4 bf16 partials -> f32 out ----------
__global__ __launch_bounds__(256) void reduce4(const unsigned short* __restrict__ P,
                                               float* __restrict__ out) {
    const int i = (blockIdx.x * 256 + threadIdx.x) * 8;   // over BB*DD
    u16x8 p0 = *(const u16x8*)(P + i);
    u16x8 p1 = *(const u16x8*)(P + (size_t)BB * DD + i);
    u16x8 p2 = *(const u16x8*)(P + (size_t)2 * BB * DD + i);
    u16x8 p3 = *(const u16x8*)(P + (size_t)3 * BB * DD + i);
    f32x4 o0, o1;
    #pragma unroll
    for (int c = 0; c < 4; ++c) {
        o0[c] = bf2f(p0[c]) + bf2f(p1[c]) + bf2f(p2[c]) + bf2f(p3[c]);
        o1[c] = bf2f(p0[4 + c]) + bf2f(p1[4 + c]) + bf2f(p2[4 + c]) + bf2f(p3[4 + c]);
    }
    *(f32x4*)(out + i) = o0;
    *(f32x4*)(out + i + 4) = o1;
}

// ---------- sparsemax over rows of S [BB][FF], in place; bf16 copy to Ab ----------
__global__ __launch_bounds__(256) void sparsemax_k(float* __restrict__ S,
                                                   unsigned short* __restrict__ Ab)
{
    __shared__ float red[8];
    const int t = threadIdx.x;
    const int w = t >> 6, lane = t & 63;
    float* Z = S + (size_t)blockIdx.x * FF;
    unsigned short* Arow = Ab + (size_t)blockIdx.x * FF;

    f32x4 z[8];
    #pragma unroll
    for (int j = 0; j < 8; ++j)
        z[j] = *(const f32x4*)&Z[j * 1024 + t * 4];

    float mx = -1e30f;
    #pragma unroll
    for (int j = 0; j < 8; ++j)
        mx = fmaxf(mx, fmaxf(fmaxf(z[j].x, z[j].y), fmaxf(z[j].z, z[j].w)));
    #pragma unroll
    for (int off = 32; off > 0; off >>= 1) mx = fmaxf(mx, __shfl_xor(mx, off));
    if (lane == 0) red[w] = mx;
    __syncthreads();
    mx = fmaxf(fmaxf(red[0], red[1]), fmaxf(red[2], red[3]));
    __syncthreads();

    float lo = mx - 1.0f, hi = mx;
    for (int it = 0; it < 24; ++it) {
        const float mid = 0.5f * (lo + hi);
        float s = 0.0f;
        #pragma unroll
        for (int j = 0; j < 8; ++j) {
            s += fmaxf(z[j].x - mid, 0.0f);
            s += fmaxf(z[j].y - mid, 0.0f);
            s += fmaxf(z[j].z - mid, 0.0f);
            s += fmaxf(z[j].w - mid, 0.0f);
        }
        #pragma unroll
        for (int off = 32; off > 0; off >>= 1) s += __shfl_xor(s, off);
        if (lane == 0) red[w] = s;
        __syncthreads();
        s = red[0] + red[1] + red[2] + red[3];
        __syncthreads();
        if (s >= 1.0f) lo = mid; else hi = mid;
    }

    float s = 0.0f, cnt = 0.0f;
    #pragma unroll
    for (int j = 0; j < 8; ++j) {
        #pragma unroll
        for (int c = 0; c < 4; ++c) {
            const float v = z[j][c];
            if (v > lo) { s += v; cnt += 1.0f; }
        }
    }
    #pragma unroll
    for (int off = 32; off > 0; off >>= 1) { s += __shfl_xor(s, off); cnt += __shfl_xor(cnt, off); }
    if (lane == 0) { red[w] = s; red[4 + w] = cnt; }
    __syncthreads();
    s   = red[0] + red[1] + red[2] + red[3];
    cnt = red[4] + red[5] + red[6] + red[7];
    const float tau = (s - 1.0f) / cnt;

    #pragma unroll
    for (int j = 0; j < 8; ++j) {
        f32x4 a;
        a.x = fmaxf(z[j].x - tau, 0.0f);
        a.y = fmaxf(z[j].y - tau, 0.0f);
        a.z = fmaxf(z[j].z - tau, 0.0f);
        a.w = fmaxf(z[j].w - tau, 0.0f);
        *(f32x4*)&Z[j * 1024 + t * 4] = a;
        u16x4 o;
        o.x = f2bf(a.x); o.y = f2bf(a.y); o.z = f2bf(a.z); o.w = f2bf(a.w);
        *(u16x4*)&Arow[j * 1024 + t * 4] = o;
    }
}

// ---------- launch ----------
extern "C" void kernel_launch(void* const* d_in, const int* in_sizes, int n_in,
                              void* d_out, int out_size, void* d_ws, size_t ws_size,
                              hipStream_t stream) {
    const float* x  = (const float*)d_in[0];
    const float* Xd = (const float*)d_in[1];
    const float* Wq = (const float*)d_in[2];
    const float* bq = (const float*)d_in[3];
    const float* Wk = (const float*)d_in[4];
    const float* bk = (const float*)d_in[5];
    const float* Wv = (const float*)d_in[6];
    const float* bv = (const float*)d_in[7];

    float* out       = (float*)d_out;
    float* out_xhat  = out + (size_t)BB * DD;
    float* out_attn  = out + (size_t)2 * BB * DD;   // scores staged here, sparsemax in place

    char* w = (char*)d_ws;
    unsigned short* xb  = (unsigned short*)w; w += (size_t)BB * DD * 2;   //  8 MB
    unsigned short* Xb  = (unsigned short*)w; w += (size_t)FF * DD * 2;   // 16 MB
    unsigned short* Wqb = (unsigned short*)w; w += (size_t)MM * DD * 2;
    unsigned short* Wkb = (unsigned short*)w; w += (size_t)MM * DD * 2;
    unsigned short* Wvb = (unsigned short*)w; w += (size_t)DD * DD * 2;
    unsigned short* Qb  = (unsigned short*)w; w += (size_t)BB * MM * 2;
    unsigned short* Kb  = (unsigned short*)w; w += (size_t)FF * MM * 2;
    unsigned short* Vtb = (unsigned short*)w; w += (size_t)DD * FF * 2;   // Vt[D][F]
    unsigned short* Ab  = (unsigned short*)w; w += (size_t)BB * FF * 2;   // attn bf16
    // split-K partials (32 MB) overlay the projection scratch (xb..Kb, 33 MB),
    // all dead by the time gemm_xhat_sk runs.
    unsigned short* Pb  = (unsigned short*)d_ws;                          // [4][BB][DD] bf16

    hipMemcpyAsync(d_out, d_in[0], (size_t)BB * DD * sizeof(float),
                   hipMemcpyDeviceToDevice, stream);

    cvt_bf16<<<BB * DD / 1024, 256, 0, stream>>>(x,  xb,  BB * DD);
    cvt_bf16<<<FF * DD / 1024, 256, 0, stream>>>(Xd, Xb,  FF * DD);
    cvt_bf16<<<MM * DD / 1024, 256, 0, stream>>>(Wq, Wqb, MM * DD);
    cvt_bf16<<<MM * DD / 1024, 256, 0, stream>>>(Wk, Wkb, MM * DD);
    cvt_bf16<<<DD * DD / 1024, 256, 0, stream>>>(Wv, Wvb, DD * DD);

    const float scl = 0.0625f;  // 1/sqrt(256)

    // Q = (x @ Wq^T + bq) * scl           [BB,MM] bf16
    gemm_bt<1, 1><<<(BB / 128) * (MM / 128), 256, 0, stream>>>(xb, Wqb, Qb, bq, BB, MM, DD, scl);
    // K = (X @ Wk^T + bk) * scl           [FF,MM] bf16
    gemm_bt<1, 1><<<(FF / 128) * (MM / 128), 256, 0, stream>>>(Xb, Wkb, Kb, bk, FF, MM, DD, scl);
    // Vt = Wv @ X^T + bv[row]             [DD,FF] bf16  (= V^T)
    gemm_bt<1, 2><<<(DD / 128) * (FF / 128), 256, 0, stream>>>(Wvb, Xb, Vtb, bv, DD, FF, DD, 1.0f);
    // scores = Q @ K^T                    [BB,FF] f32 -> d_out attn slot
    gemm_bt<0, 0><<<(BB / 128) * (FF / 128), 256, 0, stream>>>(Qb, Kb, out_attn, nullptr, BB, FF, MM, 1.0f);
    // sparsemax rows, in place + bf16 copy
    sparsemax_k<<<BB, 256, 0, stream>>>(out_attn, Ab);
    // x_hat = attn @ Vt^T via split-K x4 -> bf16 partials -> reduce
    gemm_xhat_sk<<<1024, 256, 0, stream>>>(Ab, Vtb, Pb);
    reduce4<<<BB * DD / (256 * 8), 256, 0, stream>>>(Pb, out_xhat);
}

// Round 3
// 314.850 us; speedup vs baseline: 1.3976x; 1.0714x over previous
//
#include <hip/hip_runtime.h>
#include <cstdint>
#include <cstddef>

// ---------- types & helpers ----------
typedef __attribute__((ext_vector_type(4))) float f32x4;
typedef __attribute__((ext_vector_type(8))) short bf16x8;
typedef __attribute__((ext_vector_type(4))) unsigned short u16x4;
typedef __attribute__((ext_vector_type(8))) unsigned short u16x8;

#define GPTR(p) ((const __attribute__((address_space(1))) void*)(p))
#define LPTR(p) ((__attribute__((address_space(3))) void*)(p))

static constexpr int BB = 4096;  // batch rows
static constexpr int DD = 1024;  // feature dim
static constexpr int FF = 8192;  // memory slots
static constexpr int MM = 256;   // attention key dim

__device__ __forceinline__ unsigned short f2bf(float f) {
    union { float f; unsigned u; } x; x.f = f;
    return (unsigned short)((x.u + 0x7FFFu + ((x.u >> 16) & 1u)) >> 16);  // RNE
}
__device__ __forceinline__ float bf2f(unsigned short h) {
    union { unsigned u; float f; } x; x.u = ((unsigned)h) << 16;
    return x.f;
}
// bijective XCD swizzle (grid % 8 == 0)
__device__ __forceinline__ int xcd_swz(int bid, int grid) {
    const int cpx = grid >> 3;
    return (bid & 7) * cpx + (bid >> 3);
}

// ---------- f32 -> bf16 convert ----------
__global__ __launch_bounds__(256) void cvt_bf16(const float* __restrict__ in,
                                                unsigned short* __restrict__ out, int n) {
    int i = (blockIdx.x * 256 + threadIdx.x) * 4;
    if (i >= n) return;
    f32x4 v = *(const f32x4*)(in + i);
    u16x4 o;
    o.x = f2bf(v.x); o.y = f2bf(v.y); o.z = f2bf(v.z); o.w = f2bf(v.w);
    *(u16x4*)(out + i) = o;
}

// ---------- direct C = (A @ B^T + bias) * scale ----------
template<int OUT_BF16, int BIAS_MODE>  // BIAS_MODE: 0 none, 1 by-col, 2 by-row
__global__ __launch_bounds__(256) void gemm_bt(
    const unsigned short* __restrict__ A,
    const unsigned short* __restrict__ Bm,
    void* __restrict__ Cout,
    const float* __restrict__ bias,
    int Mo, int No, int Kd, float scale)
{
    __shared__ alignas(16) unsigned short As[128 * 32];
    __shared__ alignas(16) unsigned short Bs[128 * 32];

    const int tid  = threadIdx.x;
    const int lane = tid & 63;
    const int wid  = tid >> 6;
    const int ntile = No >> 7;
    const int L = xcd_swz(blockIdx.x, gridDim.x);
    const int tm = (L / ntile) << 7;
    const int tn = (L % ntile) << 7;
    const int wm = (wid >> 1) * 64;
    const int wn = (wid & 1) * 64;
    const int lr = lane & 15;
    const int lg = lane >> 4;

    f32x4 acc[4][4] = {};

    const int srow = tid >> 2;
    const int scol = (tid & 3) << 3;
    const unsigned short* aptr = A  + (size_t)(tm + srow) * Kd + scol;
    const unsigned short* bptr = Bm + (size_t)(tn + srow) * Kd + scol;
    unsigned short* As_base = &As[wid * 512];
    unsigned short* Bs_base = &Bs[wid * 512];

    for (int k0 = 0; k0 < Kd; k0 += 32) {
        __builtin_amdgcn_global_load_lds(GPTR(aptr + k0),                   LPTR(As_base),        16, 0, 0);
        __builtin_amdgcn_global_load_lds(GPTR(aptr + (size_t)64 * Kd + k0), LPTR(As_base + 2048), 16, 0, 0);
        __builtin_amdgcn_global_load_lds(GPTR(bptr + k0),                   LPTR(Bs_base),        16, 0, 0);
        __builtin_amdgcn_global_load_lds(GPTR(bptr + (size_t)64 * Kd + k0), LPTR(Bs_base + 2048), 16, 0, 0);
        __syncthreads();

        bf16x8 af[4], bfr[4];
        #pragma unroll
        for (int mi = 0; mi < 4; ++mi)
            af[mi] = *(const bf16x8*)&As[(wm + mi * 16 + lr) * 32 + lg * 8];
        #pragma unroll
        for (int ni = 0; ni < 4; ++ni)
            bfr[ni] = *(const bf16x8*)&Bs[(wn + ni * 16 + lr) * 32 + lg * 8];

        #pragma unroll
        for (int mi = 0; mi < 4; ++mi)
            #pragma unroll
            for (int ni = 0; ni < 4; ++ni)
                acc[mi][ni] = __builtin_amdgcn_mfma_f32_16x16x32_bf16(af[mi], bfr[ni], acc[mi][ni], 0, 0, 0);
        __syncthreads();
    }

    #pragma unroll
    for (int mi = 0; mi < 4; ++mi)
        #pragma unroll
        for (int ni = 0; ni < 4; ++ni)
            #pragma unroll
            for (int r = 0; r < 4; ++r) {
                const int row = tm + wm + mi * 16 + lg * 4 + r;
                const int col = tn + wn + ni * 16 + lr;
                float v = acc[mi][ni][r];
                if (BIAS_MODE == 1) v += bias[col];
                if (BIAS_MODE == 2) v += bias[row];
                v *= scale;
                if (OUT_BF16) ((unsigned short*)Cout)[(size_t)row * No + col] = f2bf(v);
                else          ((float*)Cout)[(size_t)row * No + col] = v;
            }
}

// ---------- split-K GEMM: P[kc] = A[., chunk] @ B[., chunk]^T, bf16 partials ----------
// grid = KC * (Mo/128) * (No/128); tm fastest, kc slowest.
template<int KC>
__global__ __launch_bounds__(256) void gemm_sk(
    const unsigned short* __restrict__ A,
    const unsigned short* __restrict__ Bm,
    unsigned short* __restrict__ P,      // [KC][Mo][No] bf16
    int Mo, int No, int Kd)
{
    __shared__ alignas(16) unsigned short As[128 * 32];
    __shared__ alignas(16) unsigned short Bs[128 * 32];

    const int tid  = threadIdx.x;
    const int lane = tid & 63;
    const int wid  = tid >> 6;
    const int mt = Mo >> 7, nt = No >> 7;
    const int L  = xcd_swz(blockIdx.x, gridDim.x);
    const int tm = (L % mt) << 7;
    const int tn = ((L / mt) % nt) << 7;
    const int kc = L / (mt * nt);
    const int chunk = Kd / KC;
    const int kbase = kc * chunk;
    const int wm = (wid >> 1) * 64;
    const int wn = (wid & 1) * 64;
    const int lr = lane & 15;
    const int lg = lane >> 4;

    f32x4 acc[4][4] = {};

    const int srow = tid >> 2;
    const int scol = (tid & 3) << 3;
    const unsigned short* aptr = A  + (size_t)(tm + srow) * Kd + kbase + scol;
    const unsigned short* bptr = Bm + (size_t)(tn + srow) * Kd + kbase + scol;
    unsigned short* As_base = &As[wid * 512];
    unsigned short* Bs_base = &Bs[wid * 512];

    for (int k0 = 0; k0 < chunk; k0 += 32) {
        __builtin_amdgcn_global_load_lds(GPTR(aptr + k0),                   LPTR(As_base),        16, 0, 0);
        __builtin_amdgcn_global_load_lds(GPTR(aptr + (size_t)64 * Kd + k0), LPTR(As_base + 2048), 16, 0, 0);
        __builtin_amdgcn_global_load_lds(GPTR(bptr + k0),                   LPTR(Bs_base),        16, 0, 0);
        __builtin_amdgcn_global_load_lds(GPTR(bptr + (size_t)64 * Kd + k0), LPTR(Bs_base + 2048), 16, 0, 0);
        __syncthreads();

        bf16x8 af[4], bfr[4];
        #pragma unroll
        for (int mi = 0; mi < 4; ++mi)
            af[mi] = *(const bf16x8*)&As[(wm + mi * 16 + lr) * 32 + lg * 8];
        #pragma unroll
        for (int ni = 0; ni < 4; ++ni)
            bfr[ni] = *(const bf16x8*)&Bs[(wn + ni * 16 + lr) * 32 + lg * 8];

        #pragma unroll
        for (int mi = 0; mi < 4; ++mi)
            #pragma unroll
            for (int ni = 0; ni < 4; ++ni)
                acc[mi][ni] = __builtin_amdgcn_mfma_f32_16x16x32_bf16(af[mi], bfr[ni], acc[mi][ni], 0, 0, 0);
        __syncthreads();
    }

    unsigned short* Pk = P + (size_t)kc * Mo * No;
    #pragma unroll
    for (int mi = 0; mi < 4; ++mi)
        #pragma unroll
        for (int ni = 0; ni < 4; ++ni)
            #pragma unroll
            for (int r = 0; r < 4; ++r) {
                const int row = tm + wm + mi * 16 + lg * 4 + r;
                const int col = tn + wn + ni * 16 + lr;
                Pk[(size_t)row * No + col] = f2bf(acc[mi][ni][r]);
            }
}

// ---------- reduce KC bf16 partials ----------
// MODE 0: f32 out, no bias. MODE 1: bf16 out, (v + bias[col]) * scale, col = i & NoMask.
template<int KC, int MODE>
__global__ __launch_bounds__(256) void reduce_sk(
    const unsigned short* __restrict__ P, void* __restrict__ out,
    const float* __restrict__ bias, size_t total, int NoMask, float scale)
{
    const size_t i = ((size_t)blockIdx.x * 256 + threadIdx.x) * 8;
    float v[8] = {0,0,0,0,0,0,0,0};
    #pragma unroll
    for (int kc = 0; kc < KC; ++kc) {
        u16x8 p = *(const u16x8*)(P + kc * total + i);
        #pragma unroll
        for (int c = 0; c < 8; ++c) v[c] += bf2f(p[c]);
    }
    if (MODE == 1) {
        u16x8 o;
        #pragma unroll
        for (int c = 0; c < 8; ++c)
            o[c] = f2bf((v[c] + bias[(i + c) & NoMask]) * scale);
        *(u16x8*)((unsigned short*)out + i) = o;
    } else {
        f32x4 o0, o1;
        #pragma unroll
        for (int c = 0; c < 4; ++c) { o0[c] = v[c]; o1[c] = v[4 + c]; }
        *(f32x4*)((float*)out + i)     = o0;
        *(f32x4*)((float*)out + i + 4) = o1;
    }
}

// ---------- sparsemax over rows of bf16 scores; writes attn f32 + attn bf16 in place ----------
// tau bounds: lo = max(mx-1, (sum-1)/F) <= tau* <= hi = mx - 1/F (both provable from
// sum over support == 1). 8 bisections then 2 exact Michelot refinements.
__global__ __launch_bounds__(256) void sparsemax_k(unsigned short* __restrict__ SA,
                                                   float* __restrict__ attn)
{
    __shared__ float red[16];
    const int t = threadIdx.x;
    const int w = t >> 6, lane = t & 63;
    unsigned short* Zrow = SA + (size_t)blockIdx.x * FF;
    float* Arow = attn + (size_t)blockIdx.x * FF;

    f32x4 z[8];
    #pragma unroll
    for (int j = 0; j < 4; ++j) {
        u16x8 v = *(const u16x8*)&Zrow[j * 2048 + t * 8];
        #pragma unroll
        for (int c = 0; c < 4; ++c) {
            z[2 * j][c]     = bf2f(v[c]);
            z[2 * j + 1][c] = bf2f(v[4 + c]);
        }
    }

    // pass 1: row max + row sum
    float mx = -1e30f, sm = 0.0f;
    #pragma unroll
    for (int j = 0; j < 8; ++j)
        #pragma unroll
        for (int c = 0; c < 4; ++c) { mx = fmaxf(mx, z[j][c]); sm += z[j][c]; }
    #pragma unroll
    for (int off = 32; off > 0; off >>= 1) {
        mx = fmaxf(mx, __shfl_xor(mx, off));
        sm += __shfl_xor(sm, off);
    }
    if (lane == 0) { red[w] = mx; red[8 + w] = sm; }
    __syncthreads();
    mx = fmaxf(fmaxf(red[0], red[1]), fmaxf(red[2], red[3]));
    sm = red[8] + red[9] + red[10] + red[11];
    __syncthreads();

    float lo = fmaxf(mx - 1.0f, (sm - 1.0f) * (1.0f / (float)FF));
    float hi = mx - 1.0f / (float)FF;

    for (int it = 0; it < 8; ++it) {
        const float mid = 0.5f * (lo + hi);
        float s = 0.0f;
        #pragma unroll
        for (int j = 0; j < 8; ++j)
            #pragma unroll
            for (int c = 0; c < 4; ++c) s += fmaxf(z[j][c] - mid, 0.0f);
        #pragma unroll
        for (int off = 32; off > 0; off >>= 1) s += __shfl_xor(s, off);
        if (lane == 0) red[w] = s;
        __syncthreads();
        s = red[0] + red[1] + red[2] + red[3];
        __syncthreads();
        if (s >= 1.0f) lo = mid; else hi = mid;
    }

    // Michelot: lo <= tau* invariant; converges from below, exact at fixed point
    for (int it = 0; it < 2; ++it) {
        float s = 0.0f, cnt = 0.0f;
        #pragma unroll
        for (int j = 0; j < 8; ++j)
            #pragma unroll
            for (int c = 0; c < 4; ++c) {
                const float v = z[j][c];
                if (v > lo) { s += v; cnt += 1.0f; }
            }
        #pragma unroll
        for (int off = 32; off > 0; off >>= 1) { s += __shfl_xor(s, off); cnt += __shfl_xor(cnt, off); }
        if (lane == 0) { red[w] = s; red[8 + w] = cnt; }
        __syncthreads();
        s   = red[0] + red[1] + red[2] + red[3];
        cnt = red[8] + red[9] + red[10] + red[11];
        __syncthreads();
        lo = (s - 1.0f) / cnt;
    }
    const float tau = lo;

    #pragma unroll
    for (int j = 0; j < 4; ++j) {
        f32x4 a0, a1;
        #pragma unroll
        for (int c = 0; c < 4; ++c) {
            a0[c] = fmaxf(z[2 * j][c] - tau, 0.0f);
            a1[c] = fmaxf(z[2 * j + 1][c] - tau, 0.0f);
        }
        *(f32x4*)&Arow[j * 2048 + t * 8]     = a0;
        *(f32x4*)&Arow[j * 2048 + t * 8 + 4] = a1;
        u16x8 o;
        #pragma unroll
        for (int c = 0; c < 4; ++c) { o[c] = f2bf(a0[c]); o[4 + c] = f2bf(a1[c]); }
        *(u16x8*)&Zrow[j * 2048 + t * 8] = o;
    }
}

// ---------- launch ----------
extern "C" void kernel_launch(void* const* d_in, const int* in_sizes, int n_in,
                              void* d_out, int out_size, void* d_ws, size_t ws_size,
                              hipStream_t stream) {
    const float* x  = (const float*)d_in[0];
    const float* Xd = (const float*)d_in[1];
    const float* Wq = (const float*)d_in[2];
    const float* bq = (const float*)d_in[3];
    const float* Wk = (const float*)d_in[4];
    const float* bk = (const float*)d_in[5];
    const float* Wv = (const float*)d_in[6];
    const float* bv = (const float*)d_in[7];

    float* out       = (float*)d_out;
    float* out_xhat  = out + (size_t)BB * DD;
    float* out_attn  = out + (size_t)2 * BB * DD;

    char* w = (char*)d_ws;
    unsigned short* xb  = (unsigned short*)w; w += (size_t)BB * DD * 2;   //  8 MB
    unsigned short* Xb  = (unsigned short*)w; w += (size_t)FF * DD * 2;   // 16 MB
    unsigned short* Wqb = (unsigned short*)w; w += (size_t)MM * DD * 2;
    unsigned short* Wkb = (unsigned short*)w; w += (size_t)MM * DD * 2;
    unsigned short* Wvb = (unsigned short*)w; w += (size_t)DD * DD * 2;
    unsigned short* Qb  = (unsigned short*)w; w += (size_t)BB * MM * 2;
    unsigned short* Kb  = (unsigned short*)w; w += (size_t)FF * MM * 2;
    unsigned short* Vtb = (unsigned short*)w; w += (size_t)DD * FF * 2;   // Vt[D][F]
    unsigned short* Sb  = (unsigned short*)w; w += (size_t)BB * FF * 2;   // scores bf16 -> attn bf16 (in place)

    // x_hat split-K partials (32 MB) overlay xb..Kb (33 MB, all dead by then)
    unsigned short* Pb  = (unsigned short*)d_ws;
    // Q/K projection partials live in the (not yet written) attn region of d_out
    unsigned short* PQ  = (unsigned short*)out_attn;                       // [8][4096][256] = 16 MB
    unsigned short* PK  = PQ + (size_t)8 * BB * MM;                        // [4][8192][256] = 16 MB

    hipMemcpyAsync(d_out, d_in[0], (size_t)BB * DD * sizeof(float),
                   hipMemcpyDeviceToDevice, stream);

    cvt_bf16<<<BB * DD / 1024, 256, 0, stream>>>(x,  xb,  BB * DD);
    cvt_bf16<<<FF * DD / 1024, 256, 0, stream>>>(Xd, Xb,  FF * DD);
    cvt_bf16<<<MM * DD / 1024, 256, 0, stream>>>(Wq, Wqb, MM * DD);
    cvt_bf16<<<MM * DD / 1024, 256, 0, stream>>>(Wk, Wkb, MM * DD);
    cvt_bf16<<<DD * DD / 1024, 256, 0, stream>>>(Wv, Wvb, DD * DD);

    const float scl = 0.0625f;  // 1/sqrt(256)

    // Q = (x @ Wq^T + bq) * scl   via split-K x8  (grid 512 = 2 blocks/CU)
    gemm_sk<8><<<8 * (BB / 128) * (MM / 128), 256, 0, stream>>>(xb, Wqb, PQ, BB, MM, DD);
    // K = (X @ Wk^T + bk) * scl   via split-K x4  (grid 512)
    gemm_sk<4><<<4 * (FF / 128) * (MM / 128), 256, 0, stream>>>(Xb, Wkb, PK, FF, MM, DD);
    reduce_sk<8, 1><<<BB * MM / 2048, 256, 0, stream>>>(PQ, Qb, bq, (size_t)BB * MM, MM - 1, scl);
    reduce_sk<4, 1><<<FF * MM / 2048, 256, 0, stream>>>(PK, Kb, bk, (size_t)FF * MM, MM - 1, scl);

    // Vt = Wv @ X^T + bv[row]   [DD,FF] bf16
    gemm_bt<1, 2><<<(DD / 128) * (FF / 128), 256, 0, stream>>>(Wvb, Xb, Vtb, bv, DD, FF, DD, 1.0f);
    // scores = Q @ K^T -> bf16 Sb
    gemm_bt<1, 0><<<(BB / 128) * (FF / 128), 256, 0, stream>>>(Qb, Kb, Sb, nullptr, BB, FF, MM, 1.0f);
    // sparsemax: attn f32 -> d_out, attn bf16 in place over Sb
    sparsemax_k<<<BB, 256, 0, stream>>>(Sb, out_attn);
    // x_hat = attn @ Vt^T via split-K x4 -> bf16 partials -> f32 reduce
    gemm_sk<4><<<4 * (BB / 128) * (DD / 128), 256, 0, stream>>>(Sb, Vtb, Pb, BB, DD, FF);
    reduce_sk<4, 0><<<BB * DD / 2048, 256, 0, stream>>>(Pb, out_xhat, nullptr, (size_t)BB * DD, 0, 1.0f);
}

// Round 4
// 277.222 us; speedup vs baseline: 1.5873x; 1.1357x over previous
//
#include <hip/hip_runtime.h>
#include <cstdint>
#include <cstddef>

// ---------- types & helpers ----------
typedef __attribute__((ext_vector_type(4))) float f32x4;
typedef __attribute__((ext_vector_type(8))) short bf16x8;
typedef __attribute__((ext_vector_type(4))) unsigned short u16x4;
typedef __attribute__((ext_vector_type(8))) unsigned short u16x8;

#define GPTR(p) ((const __attribute__((address_space(1))) void*)(p))
#define LPTR(p) ((__attribute__((address_space(3))) void*)(p))

static constexpr int BB = 4096;  // batch rows
static constexpr int DD = 1024;  // feature dim
static constexpr int FF = 8192;  // memory slots
static constexpr int MM = 256;   // attention key dim

__device__ __forceinline__ unsigned short f2bf(float f) {
    union { float f; unsigned u; } x; x.f = f;
    return (unsigned short)((x.u + 0x7FFFu + ((x.u >> 16) & 1u)) >> 16);  // RNE
}
__device__ __forceinline__ float bf2f(unsigned short h) {
    union { unsigned u; float f; } x; x.u = ((unsigned)h) << 16;
    return x.f;
}
// bijective XCD swizzle (grid % 8 == 0)
__device__ __forceinline__ int xcd_swz(int bid, int grid) {
    const int cpx = grid >> 3;
    return (bid & 7) * cpx + (bid >> 3);
}

// ---------- f32 -> bf16 convert ----------
__global__ __launch_bounds__(256) void cvt_bf16(const float* __restrict__ in,
                                                unsigned short* __restrict__ out, int n) {
    int i = (blockIdx.x * 256 + threadIdx.x) * 4;
    if (i >= n) return;
    f32x4 v = *(const f32x4*)(in + i);
    u16x4 o;
    o.x = f2bf(v.x); o.y = f2bf(v.y); o.z = f2bf(v.z); o.w = f2bf(v.w);
    *(u16x4*)(out + i) = o;
}

// ---------- unified GEMM: C = (A @ B^T + bias) * scale, all dims compile-time ----------
// A[Mo][Kd], B[No][Kd] bf16. KC==1: direct out (OUT_BF16/BIAS_MODE apply).
// KC>1: bf16 partials P[kc][Mo][No]. TN_FAST picks block-index order for L2 reuse:
//   TN_FAST=1: tn fastest (keeps per-kc B-chunk L2-resident per XCD; A-slice 8x reuse)
//   TN_FAST=0: tm fastest (keeps A / B-panel hot when A is small)
template<int Mo, int No, int Kd, int KC, int OUT_BF16, int BIAS_MODE, int TN_FAST>
__global__ __launch_bounds__(256) void gemm_t(
    const unsigned short* __restrict__ A,
    const unsigned short* __restrict__ Bm,
    void* __restrict__ Cout,
    const float* __restrict__ bias, float scale)
{
    constexpr int mt = Mo >> 7, nt = No >> 7;
    constexpr int chunk = Kd / KC;

    __shared__ alignas(16) unsigned short As[128 * 32];
    __shared__ alignas(16) unsigned short Bs[128 * 32];

    const int tid  = threadIdx.x;
    const int lane = tid & 63;
    const int wid  = tid >> 6;
    const int L = xcd_swz(blockIdx.x, KC * mt * nt);
    int tm, tn, kc;
    if constexpr (TN_FAST) {
        tn = (L % nt) << 7; const int r = L / nt;
        tm = (r % mt) << 7; kc = r / mt;
    } else {
        tm = (L % mt) << 7; const int r = L / mt;
        tn = (r % nt) << 7; kc = r / nt;
    }
    const int kbase = kc * chunk;
    const int wm = (wid >> 1) * 64;
    const int wn = (wid & 1) * 64;
    const int lr = lane & 15;
    const int lg = lane >> 4;

    f32x4 acc[4][4] = {};

    const int srow = tid >> 2;
    const int scol = (tid & 3) << 3;
    const unsigned short* aptr = A  + (size_t)(tm + srow) * Kd + kbase + scol;
    const unsigned short* bptr = Bm + (size_t)(tn + srow) * Kd + kbase + scol;
    unsigned short* As_base = &As[wid * 512];   // HW adds lane*16B
    unsigned short* Bs_base = &Bs[wid * 512];

    for (int k0 = 0; k0 < chunk; k0 += 32) {
        __builtin_amdgcn_global_load_lds(GPTR(aptr + k0),                   LPTR(As_base),        16, 0, 0);
        __builtin_amdgcn_global_load_lds(GPTR(aptr + (size_t)64 * Kd + k0), LPTR(As_base + 2048), 16, 0, 0);
        __builtin_amdgcn_global_load_lds(GPTR(bptr + k0),                   LPTR(Bs_base),        16, 0, 0);
        __builtin_amdgcn_global_load_lds(GPTR(bptr + (size_t)64 * Kd + k0), LPTR(Bs_base + 2048), 16, 0, 0);
        __syncthreads();

        bf16x8 af[4], bfr[4];
        #pragma unroll
        for (int mi = 0; mi < 4; ++mi)
            af[mi] = *(const bf16x8*)&As[(wm + mi * 16 + lr) * 32 + lg * 8];
        #pragma unroll
        for (int ni = 0; ni < 4; ++ni)
            bfr[ni] = *(const bf16x8*)&Bs[(wn + ni * 16 + lr) * 32 + lg * 8];

        #pragma unroll
        for (int mi = 0; mi < 4; ++mi)
            #pragma unroll
            for (int ni = 0; ni < 4; ++ni)
                acc[mi][ni] = __builtin_amdgcn_mfma_f32_16x16x32_bf16(af[mi], bfr[ni], acc[mi][ni], 0, 0, 0);
        __syncthreads();
    }

    if constexpr (KC > 1) {
        unsigned short* Pk = (unsigned short*)Cout + (size_t)kc * Mo * No;
        #pragma unroll
        for (int mi = 0; mi < 4; ++mi)
            #pragma unroll
            for (int ni = 0; ni < 4; ++ni)
                #pragma unroll
                for (int r = 0; r < 4; ++r) {
                    const int row = tm + wm + mi * 16 + lg * 4 + r;
                    const int col = tn + wn + ni * 16 + lr;
                    Pk[(size_t)row * No + col] = f2bf(acc[mi][ni][r]);
                }
    } else {
        #pragma unroll
        for (int mi = 0; mi < 4; ++mi)
            #pragma unroll
            for (int ni = 0; ni < 4; ++ni)
                #pragma unroll
                for (int r = 0; r < 4; ++r) {
                    const int row = tm + wm + mi * 16 + lg * 4 + r;
                    const int col = tn + wn + ni * 16 + lr;
                    float v = acc[mi][ni][r];
                    if (BIAS_MODE == 1) v += bias[col];
                    if (BIAS_MODE == 2) v += bias[row];
                    v *= scale;
                    if (OUT_BF16) ((unsigned short*)Cout)[(size_t)row * No + col] = f2bf(v);
                    else          ((float*)Cout)[(size_t)row * No + col] = v;
                }
    }
}

// ---------- reduce KC bf16 partials ----------
// MODE 0: f32 out, no bias. MODE 1: bf16 out, (v + bias[col]) * scale, col = i & NoMask.
template<int KC, int MODE>
__global__ __launch_bounds__(256) void reduce_sk(
    const unsigned short* __restrict__ P, void* __restrict__ out,
    const float* __restrict__ bias, size_t total, int NoMask, float scale)
{
    const size_t i = ((size_t)blockIdx.x * 256 + threadIdx.x) * 8;
    float v[8] = {0,0,0,0,0,0,0,0};
    #pragma unroll
    for (int kc = 0; kc < KC; ++kc) {
        u16x8 p = *(const u16x8*)(P + kc * total + i);
        #pragma unroll
        for (int c = 0; c < 8; ++c) v[c] += bf2f(p[c]);
    }
    if (MODE == 1) {
        u16x8 o;
        #pragma unroll
        for (int c = 0; c < 8; ++c)
            o[c] = f2bf((v[c] + bias[(i + c) & NoMask]) * scale);
        *(u16x8*)((unsigned short*)out + i) = o;
    } else {
        f32x4 o0, o1;
        #pragma unroll
        for (int c = 0; c < 4; ++c) { o0[c] = v[c]; o1[c] = v[4 + c]; }
        *(f32x4*)((float*)out + i)     = o0;
        *(f32x4*)((float*)out + i + 4) = o1;
    }
}

// ---------- sparsemax over rows of bf16 scores; writes attn f32 + attn bf16 in place ----------
__global__ __launch_bounds__(256) void sparsemax_k(unsigned short* __restrict__ SA,
                                                   float* __restrict__ attn)
{
    __shared__ float red[16];
    const int t = threadIdx.x;
    const int w = t >> 6, lane = t & 63;
    unsigned short* Zrow = SA + (size_t)blockIdx.x * FF;
    float* Arow = attn + (size_t)blockIdx.x * FF;

    f32x4 z[8];
    #pragma unroll
    for (int j = 0; j < 4; ++j) {
        u16x8 v = *(const u16x8*)&Zrow[j * 2048 + t * 8];
        #pragma unroll
        for (int c = 0; c < 4; ++c) {
            z[2 * j][c]     = bf2f(v[c]);
            z[2 * j + 1][c] = bf2f(v[4 + c]);
        }
    }

    // pass 1: row max + row sum
    float mx = -1e30f, sm = 0.0f;
    #pragma unroll
    for (int j = 0; j < 8; ++j)
        #pragma unroll
        for (int c = 0; c < 4; ++c) { mx = fmaxf(mx, z[j][c]); sm += z[j][c]; }
    #pragma unroll
    for (int off = 32; off > 0; off >>= 1) {
        mx = fmaxf(mx, __shfl_xor(mx, off));
        sm += __shfl_xor(sm, off);
    }
    if (lane == 0) { red[w] = mx; red[8 + w] = sm; }
    __syncthreads();
    mx = fmaxf(fmaxf(red[0], red[1]), fmaxf(red[2], red[3]));
    sm = red[8] + red[9] + red[10] + red[11];
    __syncthreads();

    float lo = fmaxf(mx - 1.0f, (sm - 1.0f) * (1.0f / (float)FF));
    float hi = mx - 1.0f / (float)FF;

    for (int it = 0; it < 8; ++it) {
        const float mid = 0.5f * (lo + hi);
        float s = 0.0f;
        #pragma unroll
        for (int j = 0; j < 8; ++j)
            #pragma unroll
            for (int c = 0; c < 4; ++c) s += fmaxf(z[j][c] - mid, 0.0f);
        #pragma unroll
        for (int off = 32; off > 0; off >>= 1) s += __shfl_xor(s, off);
        if (lane == 0) red[w] = s;
        __syncthreads();
        s = red[0] + red[1] + red[2] + red[3];
        __syncthreads();
        if (s >= 1.0f) lo = mid; else hi = mid;
    }

    // Michelot: lo <= tau* invariant; converges from below, exact at fixed point
    for (int it = 0; it < 2; ++it) {
        float s = 0.0f, cnt = 0.0f;
        #pragma unroll
        for (int j = 0; j < 8; ++j)
            #pragma unroll
            for (int c = 0; c < 4; ++c) {
                const float v = z[j][c];
                if (v > lo) { s += v; cnt += 1.0f; }
            }
        #pragma unroll
        for (int off = 32; off > 0; off >>= 1) { s += __shfl_xor(s, off); cnt += __shfl_xor(cnt, off); }
        if (lane == 0) { red[w] = s; red[8 + w] = cnt; }
        __syncthreads();
        s   = red[0] + red[1] + red[2] + red[3];
        cnt = red[8] + red[9] + red[10] + red[11];
        __syncthreads();
        lo = (s - 1.0f) / cnt;
    }
    const float tau = lo;

    #pragma unroll
    for (int j = 0; j < 4; ++j) {
        f32x4 a0, a1;
        #pragma unroll
        for (int c = 0; c < 4; ++c) {
            a0[c] = fmaxf(z[2 * j][c] - tau, 0.0f);
            a1[c] = fmaxf(z[2 * j + 1][c] - tau, 0.0f);
        }
        *(f32x4*)&Arow[j * 2048 + t * 8]     = a0;
        *(f32x4*)&Arow[j * 2048 + t * 8 + 4] = a1;
        u16x8 o;
        #pragma unroll
        for (int c = 0; c < 4; ++c) { o[c] = f2bf(a0[c]); o[4 + c] = f2bf(a1[c]); }
        *(u16x8*)&Zrow[j * 2048 + t * 8] = o;
    }
}

// ---------- launch ----------
extern "C" void kernel_launch(void* const* d_in, const int* in_sizes, int n_in,
                              void* d_out, int out_size, void* d_ws, size_t ws_size,
                              hipStream_t stream) {
    const float* x  = (const float*)d_in[0];
    const float* Xd = (const float*)d_in[1];
    const float* Wq = (const float*)d_in[2];
    const float* bq = (const float*)d_in[3];
    const float* Wk = (const float*)d_in[4];
    const float* bk = (const float*)d_in[5];
    const float* Wv = (const float*)d_in[6];
    const float* bv = (const float*)d_in[7];

    float* out       = (float*)d_out;
    float* out_xhat  = out + (size_t)BB * DD;
    float* out_attn  = out + (size_t)2 * BB * DD;

    char* w = (char*)d_ws;
    unsigned short* xb  = (unsigned short*)w; w += (size_t)BB * DD * 2;   //  8 MB
    unsigned short* Xb  = (unsigned short*)w; w += (size_t)FF * DD * 2;   // 16 MB
    unsigned short* Wqb = (unsigned short*)w; w += (size_t)MM * DD * 2;
    unsigned short* Wkb = (unsigned short*)w; w += (size_t)MM * DD * 2;
    unsigned short* Wvb = (unsigned short*)w; w += (size_t)DD * DD * 2;
    unsigned short* Qb  = (unsigned short*)w; w += (size_t)BB * MM * 2;
    unsigned short* Kb  = (unsigned short*)w; w += (size_t)FF * MM * 2;
    unsigned short* Vtb = (unsigned short*)w; w += (size_t)DD * FF * 2;   // Vt[D][F]
    unsigned short* Sb  = (unsigned short*)w; w += (size_t)BB * FF * 2;   // scores bf16 -> attn bf16 (in place)

    // x_hat split-K partials (32 MB) overlay xb..Kb (33 MB, all dead by then)
    unsigned short* Pb  = (unsigned short*)d_ws;
    // Q/K projection partials live in the (not yet written) attn region of d_out
    unsigned short* PQ  = (unsigned short*)out_attn;                       // [8][4096][256] = 16 MB
    unsigned short* PK  = PQ + (size_t)8 * BB * MM;                        // [4][8192][256] = 16 MB

    hipMemcpyAsync(d_out, d_in[0], (size_t)BB * DD * sizeof(float),
                   hipMemcpyDeviceToDevice, stream);

    cvt_bf16<<<BB * DD / 1024, 256, 0, stream>>>(x,  xb,  BB * DD);
    cvt_bf16<<<FF * DD / 1024, 256, 0, stream>>>(Xd, Xb,  FF * DD);
    cvt_bf16<<<MM * DD / 1024, 256, 0, stream>>>(Wq, Wqb, MM * DD);
    cvt_bf16<<<MM * DD / 1024, 256, 0, stream>>>(Wk, Wkb, MM * DD);
    cvt_bf16<<<DD * DD / 1024, 256, 0, stream>>>(Wv, Wvb, DD * DD);

    const float scl = 0.0625f;  // 1/sqrt(256)

    // Q = (x @ Wq^T + bq) * scl   split-K x8, grid 512
    gemm_t<BB, MM, DD, 8, 0, 0, 0><<<8 * (BB/128) * (MM/128), 256, 0, stream>>>(xb, Wqb, PQ, nullptr, 1.0f);
    // K = (X @ Wk^T + bk) * scl   split-K x4, grid 512
    gemm_t<FF, MM, DD, 4, 0, 0, 0><<<4 * (FF/128) * (MM/128), 256, 0, stream>>>(Xb, Wkb, PK, nullptr, 1.0f);
    reduce_sk<8, 1><<<BB * MM / 2048, 256, 0, stream>>>(PQ, Qb, bq, (size_t)BB * MM, MM - 1, scl);
    reduce_sk<4, 1><<<FF * MM / 2048, 256, 0, stream>>>(PK, Kb, bk, (size_t)FF * MM, MM - 1, scl);

    // Vt = Wv @ X^T + bv[row]  [DD,FF] bf16 direct; tm-fastest (A=2MB cacheable)
    gemm_t<DD, FF, DD, 1, 1, 2, 0><<<(DD/128) * (FF/128), 256, 0, stream>>>(Wvb, Xb, Vtb, bv, 1.0f);
    // scores = Q @ K^T -> bf16 Sb; tn-fastest (B=4MB L2-resident per XCD)
    gemm_t<BB, FF, MM, 1, 1, 0, 1><<<(BB/128) * (FF/128), 256, 0, stream>>>(Qb, Kb, Sb, nullptr, 1.0f);
    // sparsemax: attn f32 -> d_out, attn bf16 in place over Sb
    sparsemax_k<<<BB, 256, 0, stream>>>(Sb, out_attn);
    // x_hat = attn @ Vt^T  split-K x4, tn-fastest (per-kc B-chunk 4MB resident; A-slice 8x reuse)
    gemm_t<BB, DD, FF, 4, 0, 0, 1><<<4 * (BB/128) * (DD/128), 256, 0, stream>>>(Sb, Vtb, Pb, nullptr, 1.0f);
    reduce_sk<4, 0><<<BB * DD / 2048, 256, 0, stream>>>(Pb, out_xhat, nullptr, (size_t)BB * DD, 0, 1.0f);
}

// Round 5
// 254.088 us; speedup vs baseline: 1.7318x; 1.0910x over previous
//
#include <hip/hip_runtime.h>
#include <cstdint>
#include <cstddef>

// ---------- types & helpers ----------
typedef __attribute__((ext_vector_type(4))) float f32x4;
typedef __attribute__((ext_vector_type(8))) short bf16x8;
typedef __attribute__((ext_vector_type(4))) unsigned short u16x4;
typedef __attribute__((ext_vector_type(8))) unsigned short u16x8;

#define GPTR(p) ((const __attribute__((address_space(1))) void*)(p))
#define LPTR(p) ((__attribute__((address_space(3))) void*)(p))

static constexpr int BB = 4096;  // batch rows
static constexpr int DD = 1024;  // feature dim
static constexpr int FF = 8192;  // memory slots
static constexpr int MM = 256;   // attention key dim

__device__ __forceinline__ unsigned short f2bf(float f) {
    union { float f; unsigned u; } x; x.f = f;
    return (unsigned short)((x.u + 0x7FFFu + ((x.u >> 16) & 1u)) >> 16);  // RNE
}
__device__ __forceinline__ float bf2f(unsigned short h) {
    union { unsigned u; float f; } x; x.u = ((unsigned)h) << 16;
    return x.f;
}
// bijective XCD swizzle (grid % 8 == 0)
__device__ __forceinline__ int xcd_swz(int bid, int grid) {
    const int cpx = grid >> 3;
    return (bid & 7) * cpx + (bid >> 3);
}

// ---------- f32 -> bf16 convert ----------
__global__ __launch_bounds__(256) void cvt_bf16(const float* __restrict__ in,
                                                unsigned short* __restrict__ out, int n) {
    int i = (blockIdx.x * 256 + threadIdx.x) * 4;
    if (i >= n) return;
    f32x4 v = *(const f32x4*)(in + i);
    u16x4 o;
    o.x = f2bf(v.x); o.y = f2bf(v.y); o.z = f2bf(v.z); o.w = f2bf(v.w);
    *(u16x4*)(out + i) = o;
}

// ---------- unified 128x128 GEMM (m97 structure), all dims compile-time ----------
template<int Mo, int No, int Kd, int KC, int OUT_BF16, int BIAS_MODE, int TN_FAST>
__global__ __launch_bounds__(256) void gemm_t(
    const unsigned short* __restrict__ A,
    const unsigned short* __restrict__ Bm,
    void* __restrict__ Cout,
    const float* __restrict__ bias, float scale)
{
    constexpr int mt = Mo >> 7, nt = No >> 7;
    constexpr int chunk = Kd / KC;

    __shared__ alignas(16) unsigned short As[128 * 32];
    __shared__ alignas(16) unsigned short Bs[128 * 32];

    const int tid  = threadIdx.x;
    const int lane = tid & 63;
    const int wid  = tid >> 6;
    const int L = xcd_swz(blockIdx.x, KC * mt * nt);
    int tm, tn, kc;
    if constexpr (TN_FAST) {
        tn = (L % nt) << 7; const int r = L / nt;
        tm = (r % mt) << 7; kc = r / mt;
    } else {
        tm = (L % mt) << 7; const int r = L / mt;
        tn = (r % nt) << 7; kc = r / nt;
    }
    const int kbase = kc * chunk;
    const int wm = (wid >> 1) * 64;
    const int wn = (wid & 1) * 64;
    const int lr = lane & 15;
    const int lg = lane >> 4;

    f32x4 acc[4][4] = {};

    const int srow = tid >> 2;
    const int scol = (tid & 3) << 3;
    const unsigned short* aptr = A  + (size_t)(tm + srow) * Kd + kbase + scol;
    const unsigned short* bptr = Bm + (size_t)(tn + srow) * Kd + kbase + scol;
    unsigned short* As_base = &As[wid * 512];   // HW adds lane*16B
    unsigned short* Bs_base = &Bs[wid * 512];

    for (int k0 = 0; k0 < chunk; k0 += 32) {
        __builtin_amdgcn_global_load_lds(GPTR(aptr + k0),                   LPTR(As_base),        16, 0, 0);
        __builtin_amdgcn_global_load_lds(GPTR(aptr + (size_t)64 * Kd + k0), LPTR(As_base + 2048), 16, 0, 0);
        __builtin_amdgcn_global_load_lds(GPTR(bptr + k0),                   LPTR(Bs_base),        16, 0, 0);
        __builtin_amdgcn_global_load_lds(GPTR(bptr + (size_t)64 * Kd + k0), LPTR(Bs_base + 2048), 16, 0, 0);
        __syncthreads();

        bf16x8 af[4], bfr[4];
        #pragma unroll
        for (int mi = 0; mi < 4; ++mi)
            af[mi] = *(const bf16x8*)&As[(wm + mi * 16 + lr) * 32 + lg * 8];
        #pragma unroll
        for (int ni = 0; ni < 4; ++ni)
            bfr[ni] = *(const bf16x8*)&Bs[(wn + ni * 16 + lr) * 32 + lg * 8];

        #pragma unroll
        for (int mi = 0; mi < 4; ++mi)
            #pragma unroll
            for (int ni = 0; ni < 4; ++ni)
                acc[mi][ni] = __builtin_amdgcn_mfma_f32_16x16x32_bf16(af[mi], bfr[ni], acc[mi][ni], 0, 0, 0);
        __syncthreads();
    }

    if constexpr (KC > 1) {
        unsigned short* Pk = (unsigned short*)Cout + (size_t)kc * Mo * No;
        #pragma unroll
        for (int mi = 0; mi < 4; ++mi)
            #pragma unroll
            for (int ni = 0; ni < 4; ++ni)
                #pragma unroll
                for (int r = 0; r < 4; ++r) {
                    const int row = tm + wm + mi * 16 + lg * 4 + r;
                    const int col = tn + wn + ni * 16 + lr;
                    Pk[(size_t)row * No + col] = f2bf(acc[mi][ni][r]);
                }
    } else {
        #pragma unroll
        for (int mi = 0; mi < 4; ++mi)
            #pragma unroll
            for (int ni = 0; ni < 4; ++ni)
                #pragma unroll
                for (int r = 0; r < 4; ++r) {
                    const int row = tm + wm + mi * 16 + lg * 4 + r;
                    const int col = tn + wn + ni * 16 + lr;
                    float v = acc[mi][ni][r];
                    if (BIAS_MODE == 1) v += bias[col];
                    if (BIAS_MODE == 2) v += bias[row];
                    v *= scale;
                    if (OUT_BF16) ((unsigned short*)Cout)[(size_t)row * No + col] = f2bf(v);
                    else          ((float*)Cout)[(size_t)row * No + col] = v;
                }
    }
}

// ---------- x_hat 256x256 deep-pipelined split-K GEMM ----------
// A[BB][FF] (attn bf16), B[DD][FF] (Vt bf16), P[KC][BB][DD] bf16 partials.
// 8 waves (2M x 4N), BK=32, 4-buffer LDS ring, stage distance 3, counted vmcnt(8).
// Invariant entering K-tile u: newest 8 outstanding loads = tiles u+1,u+2 -> vmcnt(8)
// forces tile u landed (FIFO oldest-first). Tail peels vmcnt(4)/vmcnt(0).
// BK=32 => LDS row stride 64B: fragment reads hit all 32 banks evenly (8/bank =
// b128 bandwidth floor) with NO swizzle; staging stays linear for global_load_lds.
template<int KC>
__global__ __launch_bounds__(512) void gemm_xhat_256(
    const unsigned short* __restrict__ A,
    const unsigned short* __restrict__ Bm,
    unsigned short* __restrict__ P)
{
    constexpr int KCH = FF / KC;      // 2048
    constexpr int NT  = KCH / 32;     // 64 K-tiles
    constexpr int mt  = BB >> 8;      // 16
    constexpr int nt  = DD >> 8;      // 4

    __shared__ alignas(16) unsigned short SH[4 * 16384];  // 128 KB: 4 bufs x (A 16KB + B 16KB)

    const int tid  = threadIdx.x;
    const int lane = tid & 63;
    const int wid  = tid >> 6;
    const int wr   = wid >> 2;        // 0-1: 128-row block
    const int wc   = wid & 3;         // 0-3: 64-col block
    const int lr   = lane & 15;
    const int lg   = lane >> 4;

    const int L  = xcd_swz(blockIdx.x, KC * mt * nt);
    const int tn = (L % nt) << 8;
    const int r0 = L / nt;
    const int tm = (r0 % mt) << 8;
    const int kc = r0 / mt;
    const size_t kbase = (size_t)kc * KCH;

    // staging: per call, thread tid covers row s*128 + (tid>>2), cols (tid&3)*8..+7.
    // LDS dest linear: buf*16384 [+8192 for B] + s*4096 + tid*8 shorts (HW adds lane*16B).
    const unsigned short* ag0 = A  + (size_t)(tm + (tid >> 2)) * FF + kbase + ((tid & 3) << 3);
    const unsigned short* bg0 = Bm + (size_t)(tn + (tid >> 2)) * FF + kbase + ((tid & 3) << 3);

    auto STAGE_A = [&](int tt) {
        const int buf = tt & 3;
        #pragma unroll
        for (int s = 0; s < 2; ++s)
            __builtin_amdgcn_global_load_lds(GPTR(ag0 + (size_t)(s * 128) * FF + tt * 32),
                LPTR(&SH[buf * 16384 + s * 4096 + wid * 512]), 16, 0, 0);
    };
    auto STAGE_B = [&](int tt) {
        const int buf = tt & 3;
        #pragma unroll
        for (int s = 0; s < 2; ++s)
            __builtin_amdgcn_global_load_lds(GPTR(bg0 + (size_t)(s * 128) * FF + tt * 32),
                LPTR(&SH[buf * 16384 + 8192 + s * 4096 + wid * 512]), 16, 0, 0);
    };

    f32x4 acc[8][4] = {};

    // prologue: stage tiles 0,1,2 (12 calls/wave); wait tile 0 (oldest 4) landed
    STAGE_A(0); STAGE_B(0);
    STAGE_A(1); STAGE_B(1);
    STAGE_A(2); STAGE_B(2);
    asm volatile("s_waitcnt vmcnt(8)" ::: "memory");
    __builtin_amdgcn_s_barrier();

    #pragma unroll 1
    for (int t = 0; t < NT; ++t) {
        if (t) {
            if (t < NT - 2)      asm volatile("s_waitcnt vmcnt(8)" ::: "memory");
            else if (t == NT-2)  asm volatile("s_waitcnt vmcnt(4)" ::: "memory");
            else                 asm volatile("s_waitcnt vmcnt(0)" ::: "memory");
            __builtin_amdgcn_s_barrier();
        }
        const int buf = t & 3;
        const unsigned short* Ab = &SH[buf * 16384];
        const unsigned short* Bb = &SH[buf * 16384 + 8192];

        // ---- phase 1: read B(all) + A(mi 0-3); stage A(t+3); 16 MFMA ----
        bf16x8 bfr[4], af[4];
        #pragma unroll
        for (int ni = 0; ni < 4; ++ni)
            bfr[ni] = *(const bf16x8*)&Bb[(wc * 64 + ni * 16 + lr) * 32 + lg * 8];
        #pragma unroll
        for (int mi = 0; mi < 4; ++mi)
            af[mi] = *(const bf16x8*)&Ab[(wr * 128 + mi * 16 + lr) * 32 + lg * 8];
        if (t + 3 < NT) STAGE_A(t + 3);
        __builtin_amdgcn_sched_barrier(0);
        __builtin_amdgcn_s_setprio(1);
        #pragma unroll
        for (int mi = 0; mi < 4; ++mi)
            #pragma unroll
            for (int ni = 0; ni < 4; ++ni)
                acc[mi][ni] = __builtin_amdgcn_mfma_f32_16x16x32_bf16(af[mi], bfr[ni], acc[mi][ni], 0, 0, 0);
        __builtin_amdgcn_s_setprio(0);
        __builtin_amdgcn_s_barrier();

        // ---- phase 2: read A(mi 4-7); stage B(t+3); 16 MFMA ----
        bf16x8 af2[4];
        #pragma unroll
        for (int mi = 0; mi < 4; ++mi)
            af2[mi] = *(const bf16x8*)&Ab[(wr * 128 + 64 + mi * 16 + lr) * 32 + lg * 8];
        if (t + 3 < NT) STAGE_B(t + 3);
        __builtin_amdgcn_sched_barrier(0);
        __builtin_amdgcn_s_setprio(1);
        #pragma unroll
        for (int mi = 0; mi < 4; ++mi)
            #pragma unroll
            for (int ni = 0; ni < 4; ++ni)
                acc[4 + mi][ni] = __builtin_amdgcn_mfma_f32_16x16x32_bf16(af2[mi], bfr[ni], acc[4 + mi][ni], 0, 0, 0);
        __builtin_amdgcn_s_setprio(0);
    }

    // epilogue: bf16 partials
    unsigned short* Pk = P + ((size_t)kc * BB + tm) * DD + tn;
    #pragma unroll
    for (int mi = 0; mi < 8; ++mi)
        #pragma unroll
        for (int ni = 0; ni < 4; ++ni)
            #pragma unroll
            for (int r = 0; r < 4; ++r) {
                const int row = wr * 128 + mi * 16 + lg * 4 + r;
                const int col = wc * 64 + ni * 16 + lr;
                Pk[(size_t)row * DD + col] = f2bf(acc[mi][ni][r]);
            }
}

// ---------- reduce KC bf16 partials ----------
template<int KC, int MODE>
__global__ __launch_bounds__(256) void reduce_sk(
    const unsigned short* __restrict__ P, void* __restrict__ out,
    const float* __restrict__ bias, size_t total, int NoMask, float scale)
{
    const size_t i = ((size_t)blockIdx.x * 256 + threadIdx.x) * 8;
    float v[8] = {0,0,0,0,0,0,0,0};
    #pragma unroll
    for (int kc = 0; kc < KC; ++kc) {
        u16x8 p = *(const u16x8*)(P + kc * total + i);
        #pragma unroll
        for (int c = 0; c < 8; ++c) v[c] += bf2f(p[c]);
    }
    if (MODE == 1) {
        u16x8 o;
        #pragma unroll
        for (int c = 0; c < 8; ++c)
            o[c] = f2bf((v[c] + bias[(i + c) & NoMask]) * scale);
        *(u16x8*)((unsigned short*)out + i) = o;
    } else {
        f32x4 o0, o1;
        #pragma unroll
        for (int c = 0; c < 4; ++c) { o0[c] = v[c]; o1[c] = v[4 + c]; }
        *(f32x4*)((float*)out + i)     = o0;
        *(f32x4*)((float*)out + i + 4) = o1;
    }
}

// ---------- sparsemax over rows of bf16 scores; attn f32 out + attn bf16 in place ----------
__global__ __launch_bounds__(256) void sparsemax_k(unsigned short* __restrict__ SA,
                                                   float* __restrict__ attn)
{
    __shared__ float red[16];
    const int t = threadIdx.x;
    const int w = t >> 6, lane = t & 63;
    unsigned short* Zrow = SA + (size_t)blockIdx.x * FF;
    float* Arow = attn + (size_t)blockIdx.x * FF;

    f32x4 z[8];
    #pragma unroll
    for (int j = 0; j < 4; ++j) {
        u16x8 v = *(const u16x8*)&Zrow[j * 2048 + t * 8];
        #pragma unroll
        for (int c = 0; c < 4; ++c) {
            z[2 * j][c]     = bf2f(v[c]);
            z[2 * j + 1][c] = bf2f(v[4 + c]);
        }
    }

    float mx = -1e30f, sm = 0.0f;
    #pragma unroll
    for (int j = 0; j < 8; ++j)
        #pragma unroll
        for (int c = 0; c < 4; ++c) { mx = fmaxf(mx, z[j][c]); sm += z[j][c]; }
    #pragma unroll
    for (int off = 32; off > 0; off >>= 1) {
        mx = fmaxf(mx, __shfl_xor(mx, off));
        sm += __shfl_xor(sm, off);
    }
    if (lane == 0) { red[w] = mx; red[8 + w] = sm; }
    __syncthreads();
    mx = fmaxf(fmaxf(red[0], red[1]), fmaxf(red[2], red[3]));
    sm = red[8] + red[9] + red[10] + red[11];
    __syncthreads();

    float lo = fmaxf(mx - 1.0f, (sm - 1.0f) * (1.0f / (float)FF));
    float hi = mx - 1.0f / (float)FF;

    for (int it = 0; it < 8; ++it) {
        const float mid = 0.5f * (lo + hi);
        float s = 0.0f;
        #pragma unroll
        for (int j = 0; j < 8; ++j)
            #pragma unroll
            for (int c = 0; c < 4; ++c) s += fmaxf(z[j][c] - mid, 0.0f);
        #pragma unroll
        for (int off = 32; off > 0; off >>= 1) s += __shfl_xor(s, off);
        if (lane == 0) red[w] = s;
        __syncthreads();
        s = red[0] + red[1] + red[2] + red[3];
        __syncthreads();
        if (s >= 1.0f) lo = mid; else hi = mid;
    }

    for (int it = 0; it < 2; ++it) {
        float s = 0.0f, cnt = 0.0f;
        #pragma unroll
        for (int j = 0; j < 8; ++j)
            #pragma unroll
            for (int c = 0; c < 4; ++c) {
                const float v = z[j][c];
                if (v > lo) { s += v; cnt += 1.0f; }
            }
        #pragma unroll
        for (int off = 32; off > 0; off >>= 1) { s += __shfl_xor(s, off); cnt += __shfl_xor(cnt, off); }
        if (lane == 0) { red[w] = s; red[8 + w] = cnt; }
        __syncthreads();
        s   = red[0] + red[1] + red[2] + red[3];
        cnt = red[8] + red[9] + red[10] + red[11];
        __syncthreads();
        lo = (s - 1.0f) / cnt;
    }
    const float tau = lo;

    #pragma unroll
    for (int j = 0; j < 4; ++j) {
        f32x4 a0, a1;
        #pragma unroll
        for (int c = 0; c < 4; ++c) {
            a0[c] = fmaxf(z[2 * j][c] - tau, 0.0f);
            a1[c] = fmaxf(z[2 * j + 1][c] - tau, 0.0f);
        }
        *(f32x4*)&Arow[j * 2048 + t * 8]     = a0;
        *(f32x4*)&Arow[j * 2048 + t * 8 + 4] = a1;
        u16x8 o;
        #pragma unroll
        for (int c = 0; c < 4; ++c) { o[c] = f2bf(a0[c]); o[4 + c] = f2bf(a1[c]); }
        *(u16x8*)&Zrow[j * 2048 + t * 8] = o;
    }
}

// ---------- launch ----------
extern "C" void kernel_launch(void* const* d_in, const int* in_sizes, int n_in,
                              void* d_out, int out_size, void* d_ws, size_t ws_size,
                              hipStream_t stream) {
    const float* x  = (const float*)d_in[0];
    const float* Xd = (const float*)d_in[1];
    const float* Wq = (const float*)d_in[2];
    const float* bq = (const float*)d_in[3];
    const float* Wk = (const float*)d_in[4];
    const float* bk = (const float*)d_in[5];
    const float* Wv = (const float*)d_in[6];
    const float* bv = (const float*)d_in[7];

    float* out       = (float*)d_out;
    float* out_xhat  = out + (size_t)BB * DD;
    float* out_attn  = out + (size_t)2 * BB * DD;

    char* w = (char*)d_ws;
    unsigned short* xb  = (unsigned short*)w; w += (size_t)BB * DD * 2;   //  8 MB
    unsigned short* Xb  = (unsigned short*)w; w += (size_t)FF * DD * 2;   // 16 MB
    unsigned short* Wqb = (unsigned short*)w; w += (size_t)MM * DD * 2;
    unsigned short* Wkb = (unsigned short*)w; w += (size_t)MM * DD * 2;
    unsigned short* Wvb = (unsigned short*)w; w += (size_t)DD * DD * 2;
    unsigned short* Qb  = (unsigned short*)w; w += (size_t)BB * MM * 2;
    unsigned short* Kb  = (unsigned short*)w; w += (size_t)FF * MM * 2;
    unsigned short* Vtb = (unsigned short*)w; w += (size_t)DD * FF * 2;   // Vt[D][F]
    unsigned short* Sb  = (unsigned short*)w; w += (size_t)BB * FF * 2;   // scores bf16 -> attn bf16 (in place)

    // x_hat split-K partials (32 MB) overlay xb..Kb (33 MB, all dead by then)
    unsigned short* Pb  = (unsigned short*)d_ws;
    // Q/K projection partials live in the (not yet written) attn region of d_out
    unsigned short* PQ  = (unsigned short*)out_attn;                       // [8][4096][256] = 16 MB
    unsigned short* PK  = PQ + (size_t)8 * BB * MM;                        // [4][8192][256] = 16 MB

    hipMemcpyAsync(d_out, d_in[0], (size_t)BB * DD * sizeof(float),
                   hipMemcpyDeviceToDevice, stream);

    cvt_bf16<<<BB * DD / 1024, 256, 0, stream>>>(x,  xb,  BB * DD);
    cvt_bf16<<<FF * DD / 1024, 256, 0, stream>>>(Xd, Xb,  FF * DD);
    cvt_bf16<<<MM * DD / 1024, 256, 0, stream>>>(Wq, Wqb, MM * DD);
    cvt_bf16<<<MM * DD / 1024, 256, 0, stream>>>(Wk, Wkb, MM * DD);
    cvt_bf16<<<DD * DD / 1024, 256, 0, stream>>>(Wv, Wvb, DD * DD);

    const float scl = 0.0625f;  // 1/sqrt(256)

    // Q = (x @ Wq^T + bq) * scl   split-K x8, grid 512
    gemm_t<BB, MM, DD, 8, 0, 0, 0><<<8 * (BB/128) * (MM/128), 256, 0, stream>>>(xb, Wqb, PQ, nullptr, 1.0f);
    // K = (X @ Wk^T + bk) * scl   split-K x4, grid 512
    gemm_t<FF, MM, DD, 4, 0, 0, 0><<<4 * (FF/128) * (MM/128), 256, 0, stream>>>(Xb, Wkb, PK, nullptr, 1.0f);
    reduce_sk<8, 1><<<BB * MM / 2048, 256, 0, stream>>>(PQ, Qb, bq, (size_t)BB * MM, MM - 1, scl);
    reduce_sk<4, 1><<<FF * MM / 2048, 256, 0, stream>>>(PK, Kb, bk, (size_t)FF * MM, MM - 1, scl);

    // Vt = Wv @ X^T + bv[row]  [DD,FF] bf16 direct; tm-fastest
    gemm_t<DD, FF, DD, 1, 1, 2, 0><<<(DD/128) * (FF/128), 256, 0, stream>>>(Wvb, Xb, Vtb, bv, 1.0f);
    // scores = Q @ K^T -> bf16 Sb; tn-fastest
    gemm_t<BB, FF, MM, 1, 1, 0, 1><<<(BB/128) * (FF/128), 256, 0, stream>>>(Qb, Kb, Sb, nullptr, 1.0f);
    // sparsemax: attn f32 -> d_out, attn bf16 in place over Sb
    sparsemax_k<<<BB, 256, 0, stream>>>(Sb, out_attn);
    // x_hat = attn @ Vt^T  deep-pipelined 256x256 split-K x4 -> bf16 partials -> f32 reduce
    gemm_xhat_256<4><<<4 * (BB/256) * (DD/256), 512, 0, stream>>>(Sb, Vtb, Pb);
    reduce_sk<4, 0><<<BB * DD / 2048, 256, 0, stream>>>(Pb, out_xhat, nullptr, (size_t)BB * DD, 0, 1.0f);
}